// Round 1
// baseline (760.162 us; speedup 1.0000x reference)
//
#include <hip/hip_runtime.h>

// TensorProduct (e3nn-style): MUL=32, DIMS=(1,3,5), Z=400000, 15 CG paths.
// One thread per (z,u). Memory-bound: ~936 MB HBM traffic -> ~150us floor.
// cg is wave-uniform with constant offsets -> compiler emits s_load; each
// inner FMA is v_fma_f32 with one SGPR operand.

namespace {
constexpr int kZ    = 400000;
constexpr int kMul  = 32;
constexpr int kDims[3] = {1, 3, 5};
constexpr int kCOff[3] = {0, 1, 4};    // compact offsets into the 9-vectors
}

__global__ __launch_bounds__(256) void tp_kernel(
    const float* __restrict__ x1,
    const float* __restrict__ x2,
    const float* __restrict__ cg,
    float* __restrict__ out)
{
    const int g = blockIdx.x * blockDim.x + threadIdx.x;
    const int u = g & (kMul - 1);
    const int z = g >> 5;
    if (z >= kZ) return;

    const float* __restrict__ x1r = x1 + (size_t)z * 288;
    const float* __restrict__ x2r = x2 + (size_t)z * 9;

    float a[9], b[9], o[9];

    // x1 row: [irrep0: 32x1][irrep1: 32x3][irrep2: 32x5]; element (u,m) at off+u*d+m
    a[0] = x1r[u];
#pragma unroll
    for (int m = 0; m < 3; ++m) a[1 + m] = x1r[32 + u * 3 + m];
#pragma unroll
    for (int m = 0; m < 5; ++m) a[4 + m] = x1r[128 + u * 5 + m];

#pragma unroll
    for (int j = 0; j < 9; ++j) b[j] = x2r[j];

#pragma unroll
    for (int k = 0; k < 9; ++k) o[k] = 0.0f;

    // res[u,k] = sum_{i,j} cg[p,i,j,k] * x1b[i1][u,i] * x2b[i2][j]
#define DO_INS(P, I1, I2, I3)                                                  \
    {                                                                          \
        constexpr int d1 = kDims[I1], d2 = kDims[I2], d3 = kDims[I3];          \
        constexpr int s1 = kCOff[I1], s2 = kCOff[I2], s3 = kCOff[I3];          \
        _Pragma("unroll")                                                      \
        for (int i = 0; i < d1; ++i) {                                         \
            _Pragma("unroll")                                                  \
            for (int j = 0; j < d2; ++j) {                                     \
                const float pij = a[s1 + i] * b[s2 + j];                       \
                _Pragma("unroll")                                              \
                for (int k = 0; k < d3; ++k) {                                 \
                    o[s3 + k] = fmaf(cg[(P) * 125 + i * 25 + j * 5 + k], pij,  \
                                     o[s3 + k]);                               \
                }                                                              \
            }                                                                  \
        }                                                                      \
    }

    DO_INS(0,  0, 0, 0)
    DO_INS(1,  0, 1, 1)
    DO_INS(2,  0, 2, 2)
    DO_INS(3,  1, 0, 1)
    DO_INS(4,  1, 1, 0)
    DO_INS(5,  1, 1, 1)
    DO_INS(6,  1, 1, 2)
    DO_INS(7,  1, 2, 1)
    DO_INS(8,  1, 2, 2)
    DO_INS(9,  2, 0, 2)
    DO_INS(10, 2, 1, 1)
    DO_INS(11, 2, 1, 2)
    DO_INS(12, 2, 2, 0)
    DO_INS(13, 2, 2, 1)
    DO_INS(14, 2, 2, 2)
#undef DO_INS

    float* __restrict__ outr = out + (size_t)z * 288;
    outr[u] = o[0];
#pragma unroll
    for (int k = 0; k < 3; ++k) outr[32 + u * 3 + k] = o[1 + k];
#pragma unroll
    for (int k = 0; k < 5; ++k) outr[128 + u * 5 + k] = o[4 + k];
}

extern "C" void kernel_launch(void* const* d_in, const int* in_sizes, int n_in,
                              void* d_out, int out_size, void* d_ws, size_t ws_size,
                              hipStream_t stream) {
    const float* x1 = (const float*)d_in[0];
    const float* x2 = (const float*)d_in[1];
    const float* cg = (const float*)d_in[2];
    float* out = (float*)d_out;

    const int total = kZ * kMul;            // 12.8M threads
    const int block = 256;
    const int grid = (total + block - 1) / block;  // 50000 blocks
    tp_kernel<<<grid, block, 0, stream>>>(x1, x2, cg, out);
}